// Round 1
// baseline (113312.659 us; speedup 1.0000x reference)
//
#include <hip/hip_runtime.h>
#include <cstdint>
#include <cstddef>

#define SEQ       32768
#define NT        512
#define START_TAG 510
#define END_TAG   511
#define NEGF      -10000.0f
#define KCH       64
#define NCH       (SEQ / KCH)   /* 512 chunks */

#define NBLK      64            /* forward blocks */
#define TPB       256           /* 4 waves/block -> 256 waves, 2 j-columns per wave */
#define WPB       4             /* waves per block */

/* workspace layout (64B aligned)
   bp  : 32 MiB  backpointers (u16)
   M   : 512 KiB chunk-composed maps
   bd  : 2 KiB   chunk boundary tags
   AgP : 8 KiB   packed (tag<<32 | alpha_bits) ping-pong slots            */
#define BP_BYTES  ((size_t)SEQ * NT * sizeof(unsigned short))
#define M_OFF     (BP_BYTES)
#define M_BYTES   ((size_t)NCH * NT * sizeof(unsigned short))
#define BD_OFF    (M_OFF + M_BYTES)
#define BD_BYTES  ((size_t)NCH * sizeof(int))
#define AG_OFF    ((BD_OFF + BD_BYTES + 63) & ~(size_t)63)

/* ---------- kernel 0: init packed alpha slots ----------
   buffer0 = (tag 0, alpha_0); buffer1 = (tag 0xFFFFFFFF, junk) -> never matches */
__global__ __launch_bounds__(NT) void init_k(unsigned long long* AgP) {
    const int t = threadIdx.x;
    const float a0 = (t == START_TAG) ? 0.0f : NEGF;
    AgP[t]      = (unsigned long long)__float_as_uint(a0);
    AgP[NT + t] = ((unsigned long long)0xFFFFFFFFu << 32)
                | (unsigned long long)__float_as_uint(NEGF);
}

/* ---------- kernel 1: barrier-free wave-owned Viterbi forward ----------
   Wave wid (0..255) owns columns j = {2*wid, 2*wid+1}.
   Lane = g*32 + m (g = column within wave, m = i-chunk lane); lane scans
   i in [16m, 16m+16) with its 16 transition values held in registers.
   Alpha exchange: one 64-bit atomic slot per tag = (step<<32)|bits(alpha);
   consumers poll the slot directly (tag IS validity -> single L3 trip).
   Parity ping-pong + full 32-bit tag gives provable >=2-step overwrite lag.
   No __syncthreads anywhere: 32-lane shfl_xor butterfly does the argmax.  */
__global__ __launch_bounds__(TPB) void viterbi_fwd(const float* __restrict__ u,
                                                   const float* __restrict__ trans,
                                                   unsigned short* __restrict__ bp,
                                                   unsigned long long* AgP) {
    __shared__ float4 aw4[WPB][NT / 4];      /* per-wave swizzled alpha, 2 KiB each */

    const int tid  = threadIdx.x;
    const int wv   = tid >> 6;               /* wave in block, 0..3 */
    const int lane = tid & 63;
    const int g    = lane >> 5;              /* column group 0..1 */
    const int m    = lane & 31;              /* i-chunk lane 0..31 */
    const int wid  = (int)blockIdx.x * WPB + wv;   /* 0..255 */
    const int j    = 2 * wid + g;            /* owned output column */
    const int i0   = 16 * m;                 /* this lane's candidate base */

    /* stage this lane's 16 transition values: trans[j][i0..i0+16) (contiguous) */
    float treg[16];
    #pragma unroll
    for (int k = 0; k < 16; ++k) treg[k] = trans[(size_t)j * NT + i0 + k];

    float* awf = (float*)&aw4[wv][0];

    /* u prefetch for t=0 (column leaders only) */
    float uval = 0.0f;
    if (m == 0) uval = u[j];

    for (int t = 0; t < SEQ; ++t) {
        /* prefetch next step's u early; hides HBM latency under this step */
        float unext = 0.0f;
        const int tn = (t + 1 < SEQ) ? (t + 1) : t;
        if (m == 0) unext = u[(size_t)tn * NT + j];

        /* poll 8 interleaved slots/lane (coalesced 512B per instruction) */
        const unsigned long long* sb = AgP + (size_t)(t & 1) * NT + lane;
        unsigned long long va[8];
        const unsigned expt = (unsigned)t;
        bool ok;
        do {
            ok = true;
            #pragma unroll
            for (int r = 0; r < 8; ++r) {
                va[r] = __hip_atomic_load(&sb[r * 64], __ATOMIC_RELAXED,
                                          __HIP_MEMORY_SCOPE_AGENT);
                ok &= ((unsigned)(va[r] >> 32) == expt);
            }
        } while (!ok);

        /* scatter to per-wave LDS, XOR-swizzled: phys(i) = i ^ (((i>>5)&7)<<2)
           -> the strided float4 re-reads below are bank-conflict-free        */
        #pragma unroll
        for (int r = 0; r < 8; ++r) {
            const int i    = r * 64 + lane;
            const int phys = i ^ (((i >> 5) & 7) << 2);
            awf[phys] = __uint_as_float((unsigned)va[r]);
        }

        /* scan 16 candidates: ascending i, strict '>' => lowest index on ties */
        float bv = -INFINITY; int bi = 0;
        #pragma unroll
        for (int kk = 0; kk < 4; ++kk) {
            const int ib = i0 + 4 * kk;
            const int pb = ib ^ (((ib >> 5) & 7) << 2);
            const float4 a4 = aw4[wv][pb >> 2];
            float s;
            s = a4.x + treg[4 * kk + 0]; if (s > bv) { bv = s; bi = ib + 0; }
            s = a4.y + treg[4 * kk + 1]; if (s > bv) { bv = s; bi = ib + 1; }
            s = a4.z + treg[4 * kk + 2]; if (s > bv) { bv = s; bi = ib + 2; }
            s = a4.w + treg[4 * kk + 3]; if (s > bv) { bv = s; bi = ib + 3; }
        }

        /* 32-lane butterfly argmax (tie: lowest i wins) */
        #pragma unroll
        for (int h = 1; h <= 16; h <<= 1) {
            const float ov = __shfl_xor(bv, h);
            const int   oi = __shfl_xor(bi, h);
            if (ov > bv || (ov == bv && oi < bi)) { bv = ov; bi = oi; }
        }

        /* backpointers: lane 0 packs both columns into one dword store */
        const int oi1 = __shfl(bi, 32);      /* g=1 result */
        if (lane == 0) {
            *(unsigned*)&bp[(size_t)t * NT + 2 * wid] =
                (unsigned)(bi & 0xFFFF) | ((unsigned)oi1 << 16);
        }

        /* publish alpha_{t+1}: value data-depends on every polled load,
           so no fence is needed for the safety argument                  */
        if (m == 0) {
            const float na = bv + uval;
            const unsigned long long pk =
                ((unsigned long long)(unsigned)(t + 1) << 32)
                | (unsigned long long)__float_as_uint(na);
            __hip_atomic_store(&AgP[(size_t)((t + 1) & 1) * NT + j], pk,
                               __ATOMIC_RELAXED, __HIP_MEMORY_SCOPE_AGENT);
        }
        uval = unext;
    }
}

/* ---------- kernel 2: parallel chunk-map composition from bp ---------- */
__global__ __launch_bounds__(NT) void mbuild_k(const unsigned short* __restrict__ bp,
                                               unsigned short* __restrict__ M) {
    __shared__ unsigned short R[2][NT];
    const int c = (int)blockIdx.x, j = threadIdx.x;
    const size_t base = (size_t)c * KCH * NT;
    R[0][j] = bp[base + j];
    int cb = 0;
    for (int t = 1; t < KCH; ++t) {
        const unsigned short r = bp[base + (size_t)t * NT + j];
        __syncthreads();
        R[cb ^ 1][j] = R[cb][r];
        cb ^= 1;
    }
    __syncthreads();
    M[(size_t)c * NT + j] = R[cb][j];
}

/* ---------- kernel 3: terminal argmax + chunk-boundary chase ---------- */
__global__ __launch_bounds__(NT) void chase_k(const unsigned long long* __restrict__ AgP,
                                              const float* __restrict__ tr,
                                              const unsigned short* __restrict__ M,
                                              int* __restrict__ boundary,
                                              float* __restrict__ out) {
    __shared__ float sv[NT];
    __shared__ int   si[NT];
    const int j = threadIdx.x;
    /* alpha_SEQ lives in buffer 0 (SEQ even); low 32 bits = float value */
    sv[j] = __uint_as_float((unsigned)AgP[j]) + tr[(size_t)END_TAG * NT + j];
    si[j] = j;
    __syncthreads();
    for (int off = NT / 2; off > 0; off >>= 1) {
        if (j < off) {
            const float a = sv[j], b = sv[j + off];
            if (b > a || (b == a && si[j + off] < si[j])) { sv[j] = b; si[j] = si[j + off]; }
        }
        __syncthreads();
    }
    if (j == 0) {
        out[SEQ] = sv[0];                 /* path_score */
        int tag = si[0];                  /* path[32767] */
        boundary[NCH - 1] = tag;
        for (int c = NCH - 1; c >= 1; --c) {
            tag = (int)M[(size_t)c * NT + tag];
            boundary[c - 1] = tag;
        }
    }
}

/* ---------- kernel 4: 512 independent per-chunk local tracebacks ---------- */
__global__ __launch_bounds__(64) void traceback_k(const unsigned short* __restrict__ bp,
                                                  const int* __restrict__ boundary,
                                                  float* __restrict__ out) {
    if (threadIdx.x != 0) return;
    const int c    = (int)blockIdx.x;
    int       tag  = boundary[c];            /* = path[(c+1)K - 1] */
    const int tend = (c + 1) * KCH - 1;
    out[tend] = (float)tag;
    for (int t = tend - 1; t >= c * KCH; --t) {
        tag = (int)bp[(size_t)(t + 1) * NT + tag];
        out[t] = (float)tag;
    }
}

extern "C" void kernel_launch(void* const* d_in, const int* in_sizes, int n_in,
                              void* d_out, int out_size, void* d_ws, size_t ws_size,
                              hipStream_t stream) {
    const float* unary = (const float*)d_in[0];   /* (32768,1,512) f32 */
    const float* trans = (const float*)d_in[1];   /* (1,512,512)   f32 */
    float* out = (float*)d_out;                   /* [0..32767]=path, [32768]=score */
    char*  ws  = (char*)d_ws;

    unsigned short*     bp       = (unsigned short*)ws;
    unsigned short*     M        = (unsigned short*)(ws + M_OFF);
    int*                boundary = (int*)(ws + BD_OFF);
    unsigned long long* AgP      = (unsigned long long*)(ws + AG_OFF);
    (void)in_sizes; (void)n_in; (void)out_size; (void)ws_size;

    init_k<<<1, NT, 0, stream>>>(AgP);
    viterbi_fwd<<<NBLK, TPB, 0, stream>>>(unary, trans, bp, AgP);
    mbuild_k<<<NCH, NT, 0, stream>>>(bp, M);
    chase_k<<<1, NT, 0, stream>>>(AgP, trans, M, boundary, out);
    traceback_k<<<NCH, 64, 0, stream>>>(bp, boundary, out);
}

// Round 2
// 59641.382 us; speedup vs baseline: 1.8999x; 1.8999x over previous
//
#include <hip/hip_runtime.h>
#include <cstdint>
#include <cstddef>

#define SEQ       32768
#define NT        512
#define START_TAG 510
#define END_TAG   511
#define NEGF      -10000.0f
#define KCH       64
#define NCH       (SEQ / KCH)   /* 512 chunks */

#define NBLK      64            /* forward blocks */
#define TPB       256           /* 4 waves/block */
#define CPB       8             /* columns owned per block (NT/NBLK) */

/* workspace layout (64B aligned)
   bp  : 32 MiB  backpointers (u16)
   M   : 512 KiB chunk-composed maps
   bd  : 2 KiB   chunk boundary tags
   AgP : 8 KiB   packed (tag<<32 | alpha_bits) ping-pong slots            */
#define BP_BYTES  ((size_t)SEQ * NT * sizeof(unsigned short))
#define M_OFF     (BP_BYTES)
#define M_BYTES   ((size_t)NCH * NT * sizeof(unsigned short))
#define BD_OFF    (M_OFF + M_BYTES)
#define BD_BYTES  ((size_t)NCH * sizeof(int))
#define AG_OFF    ((BD_OFF + BD_BYTES + 63) & ~(size_t)63)

/* ---------- kernel 0: init packed alpha slots ----------
   buffer0 = (tag 0, alpha_0); buffer1 = (tag 0xFFFFFFFF, junk) -> never matches */
__global__ __launch_bounds__(NT) void init_k(unsigned long long* AgP) {
    const int t = threadIdx.x;
    const float a0 = (t == START_TAG) ? 0.0f : NEGF;
    AgP[t]      = (unsigned long long)__float_as_uint(a0);
    AgP[NT + t] = ((unsigned long long)0xFFFFFFFFu << 32)
                | (unsigned long long)__float_as_uint(NEGF);
}

/* ---------- kernel 1: relay-polled wave-owned Viterbi forward ----------
   Block b owns columns j in [8b, 8b+8). Wave wv covers columns {8b+2wv, +1};
   lane = g*32 + m: g = column within wave, m = i-chunk lane, each lane scans
   i in [16m, 16m+16) with its 16 transition values in registers.
   Alpha exchange: one 64-bit slot per tag = (step<<32)|bits(alpha), relaxed
   agent scope. ONLY WAVE 0 of each block polls (64 pollers, not 256), with
   s_sleep backoff; it scatters to parity-ping-ponged LDS and one
   __syncthreads releases the block. Tag-in-slot = validity, so no fences;
   ping-pong parity + monotone tag give >=2-step overwrite lag.            */
__global__ __launch_bounds__(TPB) void viterbi_fwd(const float* __restrict__ u,
                                                   const float* __restrict__ trans,
                                                   unsigned short* __restrict__ bp,
                                                   unsigned long long* AgP) {
    __shared__ float4 abuf[2][NT / 4];       /* parity ping-pong, 2 KiB each */

    const int tid  = threadIdx.x;
    const int wv   = tid >> 6;               /* wave in block, 0..3 */
    const int lane = tid & 63;
    const int g    = lane >> 5;              /* column within wave 0..1 */
    const int m    = lane & 31;              /* i-chunk lane 0..31 */
    const int b    = (int)blockIdx.x;
    const int j    = b * CPB + wv * 2 + g;   /* owned output column */
    const int i0   = 16 * m;                 /* this lane's candidate base */

    /* stage this lane's 16 transition values: trans[j][i0..i0+16) (contiguous) */
    float treg[16];
    #pragma unroll
    for (int k = 0; k < 16; ++k) treg[k] = trans[(size_t)j * NT + i0 + k];

    /* u prefetch for t=0 (column leaders only) */
    float uval = 0.0f;
    if (m == 0) uval = u[j];

    for (int t = 0; t < SEQ; ++t) {
        const int par = t & 1;

        /* prefetch next step's u early; hides HBM latency under this step */
        float unext = 0.0f;
        const int tn = (t + 1 < SEQ) ? (t + 1) : t;
        if (m == 0) unext = u[(size_t)tn * NT + j];

        if (wv == 0) {
            /* single poller wave: 8 interleaved tagged slots per lane (4 KiB) */
            const unsigned long long* sb = AgP + (size_t)par * NT + lane;
            unsigned long long va[8];
            const unsigned expt = (unsigned)t;
            for (;;) {
                bool ok = true;
                #pragma unroll
                for (int r = 0; r < 8; ++r) {
                    va[r] = __hip_atomic_load(&sb[r * 64], __ATOMIC_RELAXED,
                                              __HIP_MEMORY_SCOPE_AGENT);
                    ok &= ((unsigned)(va[r] >> 32) == expt);
                }
                if (ok) break;
                __builtin_amdgcn_s_sleep(1);     /* ~64 cy backoff: cut poll duty */
            }
            /* scatter to LDS, XOR-swizzled at float4 granularity:
               phys(i) = i ^ (((i>>5)&7)<<2) -> strided b128 re-reads conflict-min */
            float* awf = (float*)&abuf[par][0];
            #pragma unroll
            for (int r = 0; r < 8; ++r) {
                const int i    = r * 64 + lane;
                const int phys = i ^ (((i >> 5) & 7) << 2);
                awf[phys] = __uint_as_float((unsigned)va[r]);
            }
        }
        __syncthreads();                         /* alpha_t visible block-wide */

        /* scan 16 candidates as 4 independent chains (dep depth ~7, not 16);
           ascending i everywhere + strict '>' => lowest index wins ties      */
        float cv[4]; int ci[4];
        #pragma unroll
        for (int kk = 0; kk < 4; ++kk) {
            const int ib = i0 + 4 * kk;
            const int pb = ib ^ (((ib >> 5) & 7) << 2);
            const float4 a4 = abuf[par][pb >> 2];
            float bv = a4.x + treg[4 * kk + 0]; int bi = ib;
            float s;
            s = a4.y + treg[4 * kk + 1]; if (s > bv) { bv = s; bi = ib + 1; }
            s = a4.z + treg[4 * kk + 2]; if (s > bv) { bv = s; bi = ib + 2; }
            s = a4.w + treg[4 * kk + 3]; if (s > bv) { bv = s; bi = ib + 3; }
            cv[kk] = bv; ci[kk] = bi;
        }
        float bv = cv[0]; int bi = ci[0];
        #pragma unroll
        for (int kk = 1; kk < 4; ++kk) {         /* ascending kk: ties keep lower i */
            if (cv[kk] > bv) { bv = cv[kk]; bi = ci[kk]; }
        }

        /* 32-lane butterfly argmax (tie: lowest i wins) */
        #pragma unroll
        for (int h = 1; h <= 16; h <<= 1) {
            const float ov = __shfl_xor(bv, h);
            const int   oi = __shfl_xor(bi, h);
            if (ov > bv || (ov == bv && oi < bi)) { bv = ov; bi = oi; }
        }

        /* backpointers: lane 0 packs the wave's two columns into one dword */
        const int oi1 = __shfl(bi, 32);          /* g=1 result */
        if (lane == 0) {
            *(unsigned*)&bp[(size_t)t * NT + b * CPB + wv * 2] =
                (unsigned)(bi & 0xFFFF) | ((unsigned)oi1 << 16);
        }

        /* publish alpha_{t+1}: tagged slot, relaxed agent store (tag=validity) */
        if (m == 0) {
            const float na = bv + uval;
            const unsigned long long pk =
                ((unsigned long long)(unsigned)(t + 1) << 32)
                | (unsigned long long)__float_as_uint(na);
            __hip_atomic_store(&AgP[(size_t)((t + 1) & 1) * NT + j], pk,
                               __ATOMIC_RELAXED, __HIP_MEMORY_SCOPE_AGENT);
        }
        uval = unext;
    }
}

/* ---------- kernel 2: parallel chunk-map composition from bp ---------- */
__global__ __launch_bounds__(NT) void mbuild_k(const unsigned short* __restrict__ bp,
                                               unsigned short* __restrict__ M) {
    __shared__ unsigned short R[2][NT];
    const int c = (int)blockIdx.x, j = threadIdx.x;
    const size_t base = (size_t)c * KCH * NT;
    R[0][j] = bp[base + j];
    int cb = 0;
    for (int t = 1; t < KCH; ++t) {
        const unsigned short r = bp[base + (size_t)t * NT + j];
        __syncthreads();
        R[cb ^ 1][j] = R[cb][r];
        cb ^= 1;
    }
    __syncthreads();
    M[(size_t)c * NT + j] = R[cb][j];
}

/* ---------- kernel 3: terminal argmax + chunk-boundary chase ---------- */
__global__ __launch_bounds__(NT) void chase_k(const unsigned long long* __restrict__ AgP,
                                              const float* __restrict__ tr,
                                              const unsigned short* __restrict__ M,
                                              int* __restrict__ boundary,
                                              float* __restrict__ out) {
    __shared__ float sv[NT];
    __shared__ int   si[NT];
    const int j = threadIdx.x;
    /* alpha_SEQ lives in buffer 0 (SEQ even); low 32 bits = float value */
    sv[j] = __uint_as_float((unsigned)AgP[j]) + tr[(size_t)END_TAG * NT + j];
    si[j] = j;
    __syncthreads();
    for (int off = NT / 2; off > 0; off >>= 1) {
        if (j < off) {
            const float a = sv[j], b = sv[j + off];
            if (b > a || (b == a && si[j + off] < si[j])) { sv[j] = b; si[j] = si[j + off]; }
        }
        __syncthreads();
    }
    if (j == 0) {
        out[SEQ] = sv[0];                 /* path_score */
        int tag = si[0];                  /* path[32767] */
        boundary[NCH - 1] = tag;
        for (int c = NCH - 1; c >= 1; --c) {
            tag = (int)M[(size_t)c * NT + tag];
            boundary[c - 1] = tag;
        }
    }
}

/* ---------- kernel 4: 512 independent per-chunk local tracebacks ---------- */
__global__ __launch_bounds__(64) void traceback_k(const unsigned short* __restrict__ bp,
                                                  const int* __restrict__ boundary,
                                                  float* __restrict__ out) {
    if (threadIdx.x != 0) return;
    const int c    = (int)blockIdx.x;
    int       tag  = boundary[c];            /* = path[(c+1)K - 1] */
    const int tend = (c + 1) * KCH - 1;
    out[tend] = (float)tag;
    for (int t = tend - 1; t >= c * KCH; --t) {
        tag = (int)bp[(size_t)(t + 1) * NT + tag];
        out[t] = (float)tag;
    }
}

extern "C" void kernel_launch(void* const* d_in, const int* in_sizes, int n_in,
                              void* d_out, int out_size, void* d_ws, size_t ws_size,
                              hipStream_t stream) {
    const float* unary = (const float*)d_in[0];   /* (32768,1,512) f32 */
    const float* trans = (const float*)d_in[1];   /* (1,512,512)   f32 */
    float* out = (float*)d_out;                   /* [0..32767]=path, [32768]=score */
    char*  ws  = (char*)d_ws;

    unsigned short*     bp       = (unsigned short*)ws;
    unsigned short*     M        = (unsigned short*)(ws + M_OFF);
    int*                boundary = (int*)(ws + BD_OFF);
    unsigned long long* AgP      = (unsigned long long*)(ws + AG_OFF);
    (void)in_sizes; (void)n_in; (void)out_size; (void)ws_size;

    init_k<<<1, NT, 0, stream>>>(AgP);
    viterbi_fwd<<<NBLK, TPB, 0, stream>>>(unary, trans, bp, AgP);
    mbuild_k<<<NCH, NT, 0, stream>>>(bp, M);
    chase_k<<<1, NT, 0, stream>>>(AgP, trans, M, boundary, out);
    traceback_k<<<NCH, 64, 0, stream>>>(bp, boundary, out);
}